// Round 5
// baseline (927.304 us; speedup 1.0000x reference)
//
#include <hip/hip_runtime.h>
#include <math.h>

// ---------------- workspace layout (bytes, all 8-aligned) ----------------
#define WS_FG    0ull                          // fg f32: 4*65536*4 = 1 MB
#define WS_REF   3145728ull                    // refmap f32: 4*2*512*512*4 = 8 MB
#define WS_WSE   19922944ull                   // W_score_eff f64 [2][128][49]
#define WS_WRE   20023296ull                   // W_ref_eff f64 [2][64][49]
#define WS_WG    20073472ull                   // gather weights f32 [3136][26]
#define WS_TIDX  20399616ull                   // top_idx int [4][512]
#define WS_GATH  20407808ull                   // gathered f32 [4][512][26]
#define WS_TRIG  20620800ull                   // trig table f32 [2][6][64]
#define WS_END   20899328ull

// ============================================================
// Kernel 1: composed weights (f64) + gather-layout copies + trig table
// ============================================================
__global__ __launch_bounds__(256) void cpn_prep_kernel(
    const float* __restrict__ w_score_reduce, const float* __restrict__ w_score,
    const float* __restrict__ w_loc, const float* __restrict__ w_fourier,
    const float* __restrict__ w_ref_reduce, const float* __restrict__ w_ref,
    double* __restrict__ wse, double* __restrict__ wre, float* __restrict__ wg,
    float* __restrict__ trig)
{
    int i = blockIdx.x * 256 + threadIdx.x;
    if (i < 12544) {                    // 2*128*49
        int o = i / 6272;
        int rem = i % 6272;
        int c = rem / 49, r = rem % 49;
        double a = 0.0;
        for (int m = 0; m < 64; ++m)
            a += (double)w_score[(o*64 + m)*49 + r] * (double)w_score_reduce[m*128 + c];
        wse[i] = a;                     // layout [o][c][r]
    } else if (i < 12544 + 6272) {      // 2*64*49
        int t = i - 12544;
        int o = t / 3136;
        int rem = t % 3136;
        int c = rem / 49, r = rem % 49;
        double a = 0.0;
        for (int m = 0; m < 32; ++m)
            a += (double)w_ref[(o*32 + m)*49 + r] * (double)w_ref_reduce[m*64 + c];
        wre[t] = a;                     // layout [o][c][r]
    } else if (i < 12544 + 6272 + 81536) { // 3136*26
        int t = i - 18816;
        int tap = t / 26, o = t % 26;
        wg[t] = (o < 2) ? w_loc[o*3136 + tap] : w_fourier[(o - 2)*3136 + tap];
    } else if (i < 100352 + 768) {      // trig table, bit-identical f32 chain
        int t = i - 100352;             // 0..767 : [cs][k][s]
        int cs = t / 384;
        int k = (t % 384) / 64, s = t % 64;
        const float TWO_PI_F = (float)6.283185307179586;
        float a1 = TWO_PI_F * (float)(k + 1);   // f32 round
        float tf = (float)s * 0.015625f;        // exact
        float ang = a1 * tf;                    // f32 round
        double av = (double)ang;
        trig[t] = (cs == 0) ? (float)cos(av) : (float)sin(av);
    }
}

// ============================================================
// Kernel 2: fused score conv (128->2, 7x7, pad3), f64 accumulation,
//   then LITERAL f32 log_softmax->exp chain.  [VERIFIED r3/r4 - UNTOUCHED]
// ============================================================
__global__ __launch_bounds__(256) void cpn_score_conv_kernel(
    const float* __restrict__ cf, const float* __restrict__ esf,
    const double* __restrict__ wse, const float* __restrict__ b_score,
    float* __restrict__ fg)
{
    __shared__ __align__(16) double wch[32][7][14];    // 25088 B
    __shared__ __align__(16) float patch[38*44];       // 6688 B
    const int tid  = threadIdx.x;
    const int b    = blockIdx.z;
    const int row0 = blockIdx.y * 32;
    const int col0 = blockIdx.x * 32;
    const int ty   = tid >> 3;      // 0..31
    const int txg  = tid & 7;       // 0..7 -> 4 cols each

    double acc0[4] = {0.0,0.0,0.0,0.0};
    double acc1[4] = {0.0,0.0,0.0,0.0};
    float sreg[6];

    {   // prefetch channel 0 (from contour_features)
        const float* sp = cf + (size_t)(b*64) * 65536;
        #pragma unroll
        for (int k = 0; k < 6; ++k) {
            int i = k*256 + tid; float v = 0.f;
            if (i < 1520) {
                int r = i/40, j = i%40;
                int gy = row0 - 3 + r, gx = col0 - 4 + j;
                if ((unsigned)gy < 256u && (unsigned)gx < 256u) v = sp[gy*256 + gx];
            }
            sreg[k] = v;
        }
    }

    for (int c = 0; c < 128; ++c) {
        if ((c & 31) == 0) {      // refresh weight chunk
            for (int i = tid; i < 32*98; i += 256) {
                int cc = i / 98, r = i % 98;
                int ky = r / 14, q = r % 14;
                int kx = q >> 1, o = q & 1;
                wch[cc][ky][q] = wse[o*6272 + (c + cc)*49 + ky*7 + kx];
            }
        }
        #pragma unroll
        for (int k = 0; k < 6; ++k) {
            int i = k*256 + tid;
            if (i < 1520) patch[(i/40)*44 + (i%40)] = sreg[k];
        }
        __syncthreads();
        if (c + 1 < 128) {   // prefetch next channel while computing this one
            int cn = c + 1;
            const float* src = (cn < 64) ? cf : esf;
            const float* sp = src + (size_t)(b*64 + (cn & 63)) * 65536;
            #pragma unroll
            for (int k = 0; k < 6; ++k) {
                int i = k*256 + tid; float v = 0.f;
                if (i < 1520) {
                    int r = i/40, j = i%40;
                    int gy = row0 - 3 + r, gx = col0 - 4 + j;
                    if ((unsigned)gy < 256u && (unsigned)gx < 256u) v = sp[gy*256 + gx];
                }
                sreg[k] = v;
            }
        }
        const int cl = c & 31;
        #pragma unroll
        for (int ky = 0; ky < 7; ++ky) {
            const float4* pr = reinterpret_cast<const float4*>(&patch[(ty+ky)*44 + txg*4]);
            float4 A = pr[0], B2 = pr[1], C2 = pr[2];
            float rv[12] = {A.x,A.y,A.z,A.w,B2.x,B2.y,B2.z,B2.w,C2.x,C2.y,C2.z,C2.w};
            const double* wp = &wch[cl][ky][0];
            #pragma unroll
            for (int kx = 0; kx < 7; ++kx) {
                double w0 = wp[2*kx], w1 = wp[2*kx+1];
                #pragma unroll
                for (int p = 0; p < 4; ++p) {
                    double v = (double)rv[p + kx + 1];
                    acc0[p] = fma(w0, v, acc0[p]);
                    acc1[p] = fma(w1, v, acc1[p]);
                }
            }
        }
        __syncthreads();
    }

    double bs0 = (double)b_score[0], bs1 = (double)b_score[1];
    int y = row0 + ty;
    #pragma unroll
    for (int p = 0; p < 4; ++p) {
        int x = col0 + txg*4 + p;
        float l0f = (float)(acc0[p] + bs0);
        float l1f = (float)(acc1[p] + bs1);
        float m  = fmaxf(l0f, l1f);
        float e0 = (float)exp((double)(l0f - m));
        float e1 = (float)exp((double)(l1f - m));
        float s  = e0 + e1;
        float lg = (float)log((double)s);
        float ls1 = (l1f - m) - lg;
        float fgv = (float)exp((double)ls1);
        fg[(size_t)b*65536 + y*256 + x] = fgv;
    }
}

// ============================================================
// Kernel 3: fused refinement conv (64->2, 7x7, pad3) -- pure f32.
//   Tile 32x32, grid (16,16,4) = 4 blocks/CU, LDS 31.8 KB.
// ============================================================
__global__ __launch_bounds__(256) void cpn_ref_conv_kernel(
    const float* __restrict__ rff, const float* __restrict__ erf,
    const double* __restrict__ wre, const float* __restrict__ b_ref,
    float* __restrict__ refmap)
{
    __shared__ __align__(16) float wlds[64][7][14];    // 25088 B
    __shared__ __align__(16) float patch[38*44];       // 6688 B
    const int tid  = threadIdx.x;
    const int b    = blockIdx.z;
    const int row0 = blockIdx.y * 32;
    const int col0 = blockIdx.x * 32;
    const int ty   = tid >> 3;      // 0..31
    const int txg  = tid & 7;       // 0..7 -> 4 cols each

    for (int i = tid; i < 64*98; i += 256) {
        int c = i / 98, r = i % 98;
        int ky = r / 14, q = r % 14;
        int kx = q >> 1, o = q & 1;
        wlds[c][ky][q] = (float)wre[o*3136 + c*49 + ky*7 + kx];
    }

    float acc0[4] = {0.f,0.f,0.f,0.f};
    float acc1[4] = {0.f,0.f,0.f,0.f};
    float sreg[6];
    {
        const float* sp = rff + (size_t)(b*32) * 262144;
        #pragma unroll
        for (int k = 0; k < 6; ++k) {
            int i = k*256 + tid; float v = 0.f;
            if (i < 1520) {
                int r = i/40, j = i%40;
                int gy = row0 - 3 + r, gx = col0 - 4 + j;
                if ((unsigned)gy < 512u && (unsigned)gx < 512u) v = sp[gy*512 + gx];
            }
            sreg[k] = v;
        }
    }

    for (int c = 0; c < 64; ++c) {
        #pragma unroll
        for (int k = 0; k < 6; ++k) {
            int i = k*256 + tid;
            if (i < 1520) patch[(i/40)*44 + (i%40)] = sreg[k];
        }
        __syncthreads();
        if (c + 1 < 64) {
            int cn = c + 1;
            const float* src = (cn < 32) ? rff : erf;
            const float* sp = src + (size_t)(b*32 + (cn & 31)) * 262144;
            #pragma unroll
            for (int k = 0; k < 6; ++k) {
                int i = k*256 + tid; float v = 0.f;
                if (i < 1520) {
                    int r = i/40, j = i%40;
                    int gy = row0 - 3 + r, gx = col0 - 4 + j;
                    if ((unsigned)gy < 512u && (unsigned)gx < 512u) v = sp[gy*512 + gx];
                }
                sreg[k] = v;
            }
        }
        #pragma unroll
        for (int ky = 0; ky < 7; ++ky) {
            const float4* pr = reinterpret_cast<const float4*>(&patch[(ty+ky)*44 + txg*4]);
            float4 A = pr[0], B2 = pr[1], C2 = pr[2];
            float rv[12] = {A.x,A.y,A.z,A.w,B2.x,B2.y,B2.z,B2.w,C2.x,C2.y,C2.z,C2.w};
            const float* wp = &wlds[c][ky][0];
            float wv[14];
            #pragma unroll
            for (int q = 0; q < 14; ++q) wv[q] = wp[q];
            #pragma unroll
            for (int kx = 0; kx < 7; ++kx) {
                float w0 = wv[2*kx], w1 = wv[2*kx+1];
                #pragma unroll
                for (int p = 0; p < 4; ++p) {
                    float v = rv[p + kx + 1];
                    acc0[p] = fmaf(w0, v, acc0[p]);
                    acc1[p] = fmaf(w1, v, acc1[p]);
                }
            }
        }
        __syncthreads();
    }

    float br0 = b_ref[0], br1 = b_ref[1];
    int y = row0 + ty;
    #pragma unroll
    for (int p = 0; p < 4; ++p) {
        int x = col0 + txg*4 + p;
        float t0 = tanhf(acc0[p] + br0);
        float t1 = tanhf(acc1[p] + br1);
        refmap[((size_t)(b*2 + 0)*512 + y)*512 + x] = t0 * 3.0f;
        refmap[((size_t)(b*2 + 1)*512 + y)*512 + x] = t1 * 3.0f;
    }
}

// ============================================================
// Kernel 4: exact top-512 on u32 fg bits (3-pass radix select),
//   ties by smallest index, bitonic (key desc, idx asc). [VERIFIED r3/r4]
// ============================================================
__device__ __forceinline__ void cpn_find_bucket(
    unsigned int* hist, unsigned int* seg, int nb, int target, int tid,
    int* s_bsel, int* s_cnt)
{
    int nseg = nb / 32;
    for (int t = tid; t < nseg; t += 1024) {
        unsigned int s = 0;
        for (int q = 0; q < 32; ++q) s += hist[t*32 + q];
        seg[t] = s;
    }
    __syncthreads();
    if (tid == 0) {
        int cum = 0, sg = 0;
        for (int jj = nseg - 1; jj >= 0; --jj) {
            int c = (int)seg[jj];
            if (cum + c >= target) { sg = jj; break; }
            cum += c;
        }
        int bs = sg*32;
        for (int jj = sg*32 + 31; jj >= sg*32; --jj) {
            int c = (int)hist[jj];
            if (cum + c >= target) { bs = jj; break; }
            cum += c;
        }
        *s_bsel = bs; *s_cnt = cum;
    }
    __syncthreads();
}

__global__ __launch_bounds__(1024) void cpn_topk_kernel(
    const float* __restrict__ fg, int* __restrict__ tidx, float* __restrict__ tscores)
{
    const int b = blockIdx.x;
    const int tid = threadIdx.x;
    const float* f = fg + (size_t)b * 65536;

    __shared__ unsigned int hist[2048];
    __shared__ unsigned int seg[64];
    __shared__ int tie[2048];
    __shared__ int sel_idx[512];
    __shared__ unsigned int skey[512];
    __shared__ int sidx[512];
    __shared__ int s_b, s_c, s_nsel, s_ntie;

    const int bitsA[3]  = {11,11,10};
    const int shiftA[3] = {21,10,0};

    unsigned int prefix = 0;
    int target = 512;
    for (int pass = 0; pass < 3; ++pass) {
        int sh = shiftA[pass], nb = 1 << bitsA[pass];
        for (int i = tid; i < 2048; i += 1024) hist[i] = 0;
        __syncthreads();
        if (pass == 0) {
            for (int i = tid; i < 65536; i += 1024) {
                unsigned int k = __float_as_uint(f[i]);
                atomicAdd(&hist[k >> 21], 1u);
            }
        } else {
            int hs = sh + bitsA[pass];
            for (int i = tid; i < 65536; i += 1024) {
                unsigned int k = __float_as_uint(f[i]);
                if ((k >> hs) == prefix)
                    atomicAdd(&hist[(k >> sh) & (nb-1)], 1u);
            }
        }
        __syncthreads();
        cpn_find_bucket(hist, seg, nb, target, tid, &s_b, &s_c);
        prefix = (prefix << bitsA[pass]) | (unsigned)s_b;
        target -= s_c;
    }
    if (tid == 0) { s_nsel = 0; s_ntie = 0; }
    __syncthreads();
    const unsigned int K = prefix;

    for (int i = tid; i < 65536; i += 1024) {
        unsigned int k = __float_as_uint(f[i]);
        if (k > K) { int q = atomicAdd(&s_nsel, 1); sel_idx[q] = i; }
        else if (k == K) { int q = atomicAdd(&s_ntie, 1); if (q < 2048) tie[q] = i; }
    }
    __syncthreads();
    int nsel = s_nsel;
    int nt = s_ntie; if (nt > 2048) nt = 2048;
    for (int q = tid; q < 2048; q += 1024) if (q >= nt) tie[q] = 0x7FFFFFFF;
    __syncthreads();

    for (int kk = 2; kk <= 2048; kk <<= 1)
        for (int jj = kk >> 1; jj > 0; jj >>= 1) {
            for (int i = tid; i < 2048; i += 1024) {
                int ixj = i ^ jj;
                if (ixj > i) {
                    int a = tie[i], c = tie[ixj];
                    bool up = ((i & kk) == 0);
                    if (up ? (a > c) : (a < c)) { tie[i] = c; tie[ixj] = a; }
                }
            }
            __syncthreads();
        }

    for (int q = tid; q < 512; q += 1024) {
        unsigned int k2; int i2;
        if (q < nsel) { i2 = sel_idx[q]; k2 = __float_as_uint(f[i2]); }
        else          { i2 = tie[q - nsel]; k2 = K; }
        skey[q] = k2; sidx[q] = i2;
    }
    __syncthreads();
    for (int kk = 2; kk <= 512; kk <<= 1)
        for (int jj = kk >> 1; jj > 0; jj >>= 1) {
            if (tid < 512) {
                int i = tid, ixj = i ^ jj;
                if (ixj > i) {
                    unsigned int ka = skey[i], kc = skey[ixj];
                    int ia = sidx[i], ic = sidx[ixj];
                    bool up = ((i & kk) == 0);
                    bool aBefore = (ka > kc) || (ka == kc && ia < ic);
                    if (up ? !aBefore : aBefore) {
                        skey[i] = kc; skey[ixj] = ka;
                        sidx[i] = ic; sidx[ixj] = ia;
                    }
                }
            }
            __syncthreads();
        }
    for (int q = tid; q < 512; q += 1024) {
        int i2 = sidx[q];
        tscores[b*512 + q] = f[i2];
        tidx[b*512 + q] = i2;
    }
}

// ============================================================
// Kernel 5: gathered 7x7x64 conv at top-k pts; f64 accum -> f32 out
// ============================================================
__global__ __launch_bounds__(256) void cpn_gather_conv_kernel(
    const float* __restrict__ cf, const float* __restrict__ wg,
    const float* __restrict__ b_loc, const float* __restrict__ b_fourier,
    const int* __restrict__ tidx, float* __restrict__ gath)
{
    const int b = blockIdx.y, p = blockIdx.x, tid = threadIdx.x;
    const int idx = tidx[b*512 + p];
    const int gy = idx >> 8, gx = idx & 255;

    double part[26];
    #pragma unroll
    for (int o = 0; o < 26; ++o) part[o] = 0.0;

    for (int t = tid; t < 3136; t += 256) {
        int c = t / 49, rr = t % 49, ky = rr / 7, kx = rr % 7;
        int y = gy + ky - 3, x = gx + kx - 3;
        float v = 0.f;
        if ((unsigned)y < 256u && (unsigned)x < 256u)
            v = cf[((size_t)(b*64 + c)*256 + y)*256 + x];
        const float* wr = wg + t*26;
        double dv = (double)v;
        #pragma unroll
        for (int o = 0; o < 26; ++o) part[o] = fma(dv, (double)wr[o], part[o]);
    }
    #pragma unroll
    for (int o = 0; o < 26; ++o)
        for (int off = 32; off; off >>= 1) part[o] += __shfl_down(part[o], off, 64);

    __shared__ double red[4][26];
    int w = tid >> 6, lane = tid & 63;
    if (lane == 0) {
        #pragma unroll
        for (int o = 0; o < 26; ++o) red[w][o] = part[o];
    }
    __syncthreads();
    if (tid < 26) {
        double s = red[0][tid] + red[1][tid] + red[2][tid] + red[3][tid];
        s += (tid < 2) ? (double)b_loc[tid] : (double)b_fourier[tid - 2];
        gath[((size_t)b*512 + p)*26 + tid] = (float)s;   // f32 layer boundary
    }
}

// ============================================================
// Kernel 6: fourier synthesis (table trig) + 4 refinement iters + boxes,
//   full f32 emulation (asm barriers block FMA contraction).
// ============================================================
__global__ __launch_bounds__(64) void cpn_contour_kernel(
    const float* __restrict__ gath, const int* __restrict__ tidx,
    const float* __restrict__ refmap, const float* __restrict__ trig,
    float* __restrict__ out_contour, float* __restrict__ out_boxes)
{
    const int bp = blockIdx.x;            // b*512 + p
    const int b = bp >> 9;
    const int s = threadIdx.x;            // 0..63
    const float* g = gath + (size_t)bp * 26;
    const int idx = tidx[bp];
    const int gy = idx >> 8, gx = idx & 255;

    float cx = ((float)gx + g[0]) * 2.0f;
    float cy = ((float)gy + g[1]) * 2.0f;

    float sxc = 0.f, sxs = 0.f, syc = 0.f, sys = 0.f;
    #pragma unroll
    for (int k = 0; k < 6; ++k) {
        float cs = trig[k*64 + s];
        float sn = trig[384 + k*64 + s];
        float t0 = g[2 + k*4 + 0] * cs; asm volatile("" : "+v"(t0)); sxc += t0;
        float t1 = g[2 + k*4 + 1] * sn; asm volatile("" : "+v"(t1)); sxs += t1;
        float t2 = g[2 + k*4 + 2] * cs; asm volatile("" : "+v"(t2)); syc += t2;
        float t3 = g[2 + k*4 + 3] * sn; asm volatile("" : "+v"(t3)); sys += t3;
    }
    float px = sxc + sxs;
    float py = syc + sys;
    float x = px * 2.0f; asm volatile("" : "+v"(x)); x += cx;
    float y = py * 2.0f; asm volatile("" : "+v"(y)); y += cy;

    const float* r0 = refmap + (size_t)b * 2 * 262144;
    const float* r1 = r0 + 262144;
    #pragma unroll
    for (int it = 0; it < 4; ++it) {
        float xr = rintf(x); xr = fminf(fmaxf(xr, 0.f), 511.f);
        float yr = rintf(y); yr = fminf(fmaxf(yr, 0.f), 511.f);
        int xi = (int)xr, yi = (int)yr;
        x += r0[yi*512 + xi];
        y += r1[yi*512 + xi];
    }

    out_contour[((size_t)bp*64 + s)*2 + 0] = x;
    out_contour[((size_t)bp*64 + s)*2 + 1] = y;

    float mnx = x, mxx = x, mny = y, mxy = y;
    #pragma unroll
    for (int off = 32; off; off >>= 1) {
        mnx = fminf(mnx, __shfl_xor(mnx, off, 64));
        mny = fminf(mny, __shfl_xor(mny, off, 64));
        mxx = fmaxf(mxx, __shfl_xor(mxx, off, 64));
        mxy = fmaxf(mxy, __shfl_xor(mxy, off, 64));
    }
    if (s == 0) {
        out_boxes[bp*4 + 0] = mnx;
        out_boxes[bp*4 + 1] = mny;
        out_boxes[bp*4 + 2] = mxx;
        out_boxes[bp*4 + 3] = mxy;
    }
}

// ============================================================
// Kernel 7: sequential NMS, literal f32 op order (reference semantics)
// ============================================================
__global__ __launch_bounds__(512) void cpn_nms_kernel(
    const float* __restrict__ boxes, const float* __restrict__ scores,
    float* __restrict__ keep_out)
{
    const int b = blockIdx.x;
    const int j = threadIdx.x;
    __shared__ float X1[512], Y1[512], X2[512], Y2[512], AR[512];
    __shared__ int keep[512];

    const float* bb = boxes + b*512*4;
    float x1 = bb[j*4+0], y1 = bb[j*4+1], x2 = bb[j*4+2], y2 = bb[j*4+3];
    float aj = fmaxf(x2 - x1, 0.f) * fmaxf(y2 - y1, 0.f);
    X1[j] = x1; Y1[j] = y1; X2[j] = x2; Y2[j] = y2; AR[j] = aj;
    keep[j] = (scores[b*512 + j] > 0.5f) ? 1 : 0;
    __syncthreads();

    for (int i = 0; i < 512; ++i) {
        if (keep[i] && j > i) {
            float ix1 = fmaxf(x1, X1[i]);
            float iy1 = fmaxf(y1, Y1[i]);
            float ix2 = fminf(x2, X2[i]);
            float iy2 = fminf(y2, Y2[i]);
            float inter = fmaxf(ix2 - ix1, 0.f) * fmaxf(iy2 - iy1, 0.f);
            float uni = (aj + AR[i]) - inter;
            float iou = inter / fmaxf(uni, 1e-8f);
            if (iou > 0.2f) keep[j] = 0;
        }
        __syncthreads();
    }
    keep_out[b*512 + j] = keep[j] ? 1.0f : 0.0f;
}

// ============================================================
extern "C" void kernel_launch(void* const* d_in, const int* in_sizes, int n_in,
                              void* d_out, int out_size, void* d_ws, size_t ws_size,
                              hipStream_t stream)
{
    if (ws_size < WS_END) return;   // defensive: avoid OOB scratch writes

    const float* cf   = (const float*)d_in[0];   // contour_features (4,64,256,256)
    const float* esf  = (const float*)d_in[1];   // enc_score_features
    const float* rff  = (const float*)d_in[2];   // refinement_features (4,32,512,512)
    const float* erf  = (const float*)d_in[3];   // enc_refinement_features
    const float* w_sr = (const float*)d_in[4];   // w_score_reduce (64,128,1,1)
    const float* w_s  = (const float*)d_in[5];   // w_score (2,64,7,7)
    const float* b_s  = (const float*)d_in[6];
    const float* w_l  = (const float*)d_in[7];   // w_loc (2,64,7,7)
    const float* b_l  = (const float*)d_in[8];
    const float* w_f  = (const float*)d_in[9];   // w_fourier (24,64,7,7)
    const float* b_f  = (const float*)d_in[10];
    const float* w_rr = (const float*)d_in[11];  // w_ref_reduce (32,64,1,1)
    const float* w_r  = (const float*)d_in[12];  // w_ref (2,32,7,7)
    const float* b_r  = (const float*)d_in[13];

    char* ws = (char*)d_ws;
    float*  fg   = (float*)(ws + WS_FG);
    float*  refm = (float*)(ws + WS_REF);
    double* wse  = (double*)(ws + WS_WSE);
    double* wre  = (double*)(ws + WS_WRE);
    float*  wg   = (float*)(ws + WS_WG);
    int*    tidx = (int*)(ws + WS_TIDX);
    float*  gath = (float*)(ws + WS_GATH);
    float*  trig = (float*)(ws + WS_TRIG);

    float* out_contour = (float*)d_out;                  // 4*512*64*2
    float* out_scores  = out_contour + 262144;           // 4*512
    float* out_keep    = out_scores + 2048;              // 4*512
    float* out_boxes   = out_keep + 2048;                // 4*512*4

    cpn_prep_kernel<<<dim3(395), dim3(256), 0, stream>>>(
        w_sr, w_s, w_l, w_f, w_rr, w_r, wse, wre, wg, trig);
    cpn_score_conv_kernel<<<dim3(8, 8, 4), dim3(256), 0, stream>>>(
        cf, esf, wse, b_s, fg);
    cpn_ref_conv_kernel<<<dim3(16, 16, 4), dim3(256), 0, stream>>>(
        rff, erf, wre, b_r, refm);
    cpn_topk_kernel<<<dim3(4), dim3(1024), 0, stream>>>(fg, tidx, out_scores);
    cpn_gather_conv_kernel<<<dim3(512, 4), dim3(256), 0, stream>>>(
        cf, wg, b_l, b_f, tidx, gath);
    cpn_contour_kernel<<<dim3(2048), dim3(64), 0, stream>>>(
        gath, tidx, refm, trig, out_contour, out_boxes);
    cpn_nms_kernel<<<dim3(4), dim3(512), 0, stream>>>(
        out_boxes, out_scores, out_keep);
}

// Round 6
// 725.345 us; speedup vs baseline: 1.2784x; 1.2784x over previous
//
#include <hip/hip_runtime.h>
#include <math.h>

// ---------------- workspace layout (bytes, all 16-aligned) ----------------
#define WS_FG    0ull                          // fg f32: 4*65536*4 = 1 MB
#define WS_REF   3145728ull                    // refmap f32: 4*2*512*512*4 = 8 MB
#define WS_PART  11534336ull                   // score partials double2 [2][4][65536] = 8 MB
#define WS_WSE   19922944ull                   // W_score_eff f64 [2][128][49]
#define WS_WRE   20023296ull                   // W_ref_eff f64 [2][64][49]
#define WS_WG    20073472ull                   // gather weights f32 [3136][26]
#define WS_TIDX  20399616ull                   // top_idx int [4][512]
#define WS_GATH  20407808ull                   // gathered f32 [4][512][26]
#define WS_TRIG  20620800ull                   // trig table f32 [2][6][64]
#define WS_END   20899328ull

// ============================================================
// Kernel 1: composed weights (f64) + gather-layout copies + trig table
// ============================================================
__global__ __launch_bounds__(256) void cpn_prep_kernel(
    const float* __restrict__ w_score_reduce, const float* __restrict__ w_score,
    const float* __restrict__ w_loc, const float* __restrict__ w_fourier,
    const float* __restrict__ w_ref_reduce, const float* __restrict__ w_ref,
    double* __restrict__ wse, double* __restrict__ wre, float* __restrict__ wg,
    float* __restrict__ trig)
{
    int i = blockIdx.x * 256 + threadIdx.x;
    if (i < 12544) {                    // 2*128*49
        int o = i / 6272;
        int rem = i % 6272;
        int c = rem / 49, r = rem % 49;
        double a = 0.0;
        for (int m = 0; m < 64; ++m)
            a += (double)w_score[(o*64 + m)*49 + r] * (double)w_score_reduce[m*128 + c];
        wse[i] = a;                     // layout [o][c][r]
    } else if (i < 12544 + 6272) {      // 2*64*49
        int t = i - 12544;
        int o = t / 3136;
        int rem = t % 3136;
        int c = rem / 49, r = rem % 49;
        double a = 0.0;
        for (int m = 0; m < 32; ++m)
            a += (double)w_ref[(o*32 + m)*49 + r] * (double)w_ref_reduce[m*64 + c];
        wre[t] = a;                     // layout [o][c][r]
    } else if (i < 12544 + 6272 + 81536) { // 3136*26
        int t = i - 18816;
        int tap = t / 26, o = t % 26;
        wg[t] = (o < 2) ? w_loc[o*3136 + tap] : w_fourier[(o - 2)*3136 + tap];
    } else if (i < 100352 + 768) {      // trig table, bit-identical f32 chain
        int t = i - 100352;             // 0..767 : [cs][k][s]
        int cs = t / 384;
        int k = (t % 384) / 64, s = t % 64;
        const float TWO_PI_F = (float)6.283185307179586;
        float a1 = TWO_PI_F * (float)(k + 1);   // f32 round
        float tf = (float)s * 0.015625f;        // exact
        float ang = a1 * tf;                    // f32 round
        double av = (double)ang;
        trig[t] = (cs == 0) ? (float)cos(av) : (float)sin(av);
    }
}

// ============================================================
// Kernel 2a: score conv HALF (64 channels), f64 accumulation.
//   blockIdx.z = b*2 + half; half0 reads cf, half1 reads esf.
//   Writes double2 (l0,l1) partials. Inner structure = verified r3/r4.
// ============================================================
__global__ __launch_bounds__(256) void cpn_score_conv_kernel(
    const float* __restrict__ cf, const float* __restrict__ esf,
    const double* __restrict__ wse, double2* __restrict__ partial)
{
    __shared__ __align__(16) double wch[32][7][14];    // 25088 B
    __shared__ __align__(16) float patch[38*44];       // 6688 B
    const int tid  = threadIdx.x;
    const int b    = blockIdx.z >> 1;
    const int half = blockIdx.z & 1;
    const int c0   = half * 64;
    const float* src = half ? esf : cf;
    const int row0 = blockIdx.y * 32;
    const int col0 = blockIdx.x * 32;
    const int ty   = tid >> 3;      // 0..31
    const int txg  = tid & 7;       // 0..7 -> 4 cols each

    double acc0[4] = {0.0,0.0,0.0,0.0};
    double acc1[4] = {0.0,0.0,0.0,0.0};
    float sreg[6];

    {   // prefetch channel 0 of this half's source
        const float* sp = src + (size_t)(b*64) * 65536;
        #pragma unroll
        for (int k = 0; k < 6; ++k) {
            int i = k*256 + tid; float v = 0.f;
            if (i < 1520) {
                int r = i/40, j = i%40;
                int gy = row0 - 3 + r, gx = col0 - 4 + j;
                if ((unsigned)gy < 256u && (unsigned)gx < 256u) v = sp[gy*256 + gx];
            }
            sreg[k] = v;
        }
    }

    for (int c = 0; c < 64; ++c) {
        if ((c & 31) == 0) {      // refresh weight chunk
            for (int i = tid; i < 32*98; i += 256) {
                int cc = i / 98, r = i % 98;
                int ky = r / 14, q = r % 14;
                int kx = q >> 1, o = q & 1;
                wch[cc][ky][q] = wse[o*6272 + (c0 + c + cc)*49 + ky*7 + kx];
            }
        }
        #pragma unroll
        for (int k = 0; k < 6; ++k) {
            int i = k*256 + tid;
            if (i < 1520) patch[(i/40)*44 + (i%40)] = sreg[k];
        }
        __syncthreads();
        if (c + 1 < 64) {   // prefetch next channel while computing this one
            const float* sp = src + (size_t)(b*64 + (c+1)) * 65536;
            #pragma unroll
            for (int k = 0; k < 6; ++k) {
                int i = k*256 + tid; float v = 0.f;
                if (i < 1520) {
                    int r = i/40, j = i%40;
                    int gy = row0 - 3 + r, gx = col0 - 4 + j;
                    if ((unsigned)gy < 256u && (unsigned)gx < 256u) v = sp[gy*256 + gx];
                }
                sreg[k] = v;
            }
        }
        const int cl = c & 31;
        #pragma unroll
        for (int ky = 0; ky < 7; ++ky) {
            const float4* pr = reinterpret_cast<const float4*>(&patch[(ty+ky)*44 + txg*4]);
            float4 A = pr[0], B2 = pr[1], C2 = pr[2];
            float rv[12] = {A.x,A.y,A.z,A.w,B2.x,B2.y,B2.z,B2.w,C2.x,C2.y,C2.z,C2.w};
            const double* wp = &wch[cl][ky][0];
            #pragma unroll
            for (int kx = 0; kx < 7; ++kx) {
                double w0 = wp[2*kx], w1 = wp[2*kx+1];
                #pragma unroll
                for (int p = 0; p < 4; ++p) {
                    double v = (double)rv[p + kx + 1];
                    acc0[p] = fma(w0, v, acc0[p]);
                    acc1[p] = fma(w1, v, acc1[p]);
                }
            }
        }
        __syncthreads();
    }

    int y = row0 + ty;
    #pragma unroll
    for (int p = 0; p < 4; ++p) {
        int x = col0 + txg*4 + p;
        double2 v; v.x = acc0[p]; v.y = acc1[p];
        partial[(size_t)(half*4 + b)*65536 + y*256 + x] = v;
    }
}

// ============================================================
// Kernel 2b: score finalize: sum halves + bias, then LITERAL f32
//   log_softmax->exp chain (verified r3/r4).
// ============================================================
__global__ __launch_bounds__(256) void cpn_score_fin_kernel(
    const double2* __restrict__ partial, const float* __restrict__ b_score,
    float* __restrict__ fg)
{
    int i = blockIdx.x * 256 + threadIdx.x;    // 0..262143
    int b = i >> 16, px = i & 65535;
    double2 p0 = partial[(size_t)b*65536 + px];
    double2 p1 = partial[(size_t)(4 + b)*65536 + px];
    double bs0 = (double)b_score[0], bs1 = (double)b_score[1];
    float l0f = (float)((p0.x + p1.x) + bs0);
    float l1f = (float)((p0.y + p1.y) + bs1);
    float m  = fmaxf(l0f, l1f);
    float e0 = (float)exp((double)(l0f - m));
    float e1 = (float)exp((double)(l1f - m));
    float s  = e0 + e1;
    float lg = (float)log((double)s);
    float ls1 = (l1f - m) - lg;
    float fgv = (float)exp((double)ls1);
    fg[i] = fgv;
}

// ============================================================
// Kernel 3: refinement conv (64->2, 7x7, pad3), pure f32.
//   64x32 tile, 1 row x 8 px/thread, stride-76 conflict-free b128 reads.
//   Accumulation order (c,ky,kx) bit-identical to r5 (verified).
// ============================================================
__global__ __launch_bounds__(256) void cpn_ref_conv_kernel(
    const float* __restrict__ rff, const float* __restrict__ erf,
    const double* __restrict__ wre, const float* __restrict__ b_ref,
    float* __restrict__ refmap)
{
    __shared__ __align__(16) float4 patch4[38][19];    // 38 rows x 76 floats = 11552 B
    __shared__ __align__(16) float wlds[64][7][14];    // 25088 B  (total 36.6 KB)
    const int tid  = threadIdx.x;
    const int b    = blockIdx.z;
    const int row0 = blockIdx.y * 32;
    const int col0 = blockIdx.x * 64;
    const int txg  = tid & 7;       // 8 px each
    const int tyg  = tid >> 3;      // 0..31 -> 1 output row each

    for (int i = tid; i < 64*98; i += 256) {
        int c = i / 98, r = i % 98;
        int ky = r / 14, q = r % 14;
        int kx = q >> 1, o = q & 1;
        wlds[c][ky][q] = (float)wre[o*3136 + c*49 + ky*7 + kx];
    }

    // precompute staging slots (constant per thread): 38 rows x 18 float4 = 684
    int   st_r[3], st_f[3];
    long  st_off[3];
    bool  st_ok[3];
    #pragma unroll
    for (int k = 0; k < 3; ++k) {
        int i = k*256 + tid;
        int r = i / 18, f = i % 18;
        int gy = row0 - 3 + r, gx = col0 - 4 + 4*f;
        st_r[k] = r; st_f[k] = f;
        st_ok[k] = (i < 684) && ((unsigned)gy < 512u) && ((unsigned)gx < 509u);
        st_off[k] = (long)gy * 512 + gx;
    }

    float4 s4[3];
    {   // prefetch channel 0
        const float* sp = rff + (size_t)(b*32) * 262144;
        #pragma unroll
        for (int k = 0; k < 3; ++k) {
            float4 v = {0.f,0.f,0.f,0.f};
            if (st_ok[k]) v = *reinterpret_cast<const float4*>(sp + st_off[k]);
            s4[k] = v;
        }
    }

    float acc0[8] = {0,0,0,0,0,0,0,0};
    float acc1[8] = {0,0,0,0,0,0,0,0};

    for (int c = 0; c < 64; ++c) {
        #pragma unroll
        for (int k = 0; k < 3; ++k) {
            int i = k*256 + tid;
            if (i < 684) patch4[st_r[k]][st_f[k]] = s4[k];
        }
        __syncthreads();
        if (c + 1 < 64) {
            int cn = c + 1;
            const float* src = (cn < 32) ? rff : erf;
            const float* sp = src + (size_t)(b*32 + (cn & 31)) * 262144;
            #pragma unroll
            for (int k = 0; k < 3; ++k) {
                float4 v = {0.f,0.f,0.f,0.f};
                if (st_ok[k]) v = *reinterpret_cast<const float4*>(sp + st_off[k]);
                s4[k] = v;
            }
        }
        #pragma unroll
        for (int pr = 0; pr < 7; ++pr) {       // pr == ky
            int row = tyg + pr;
            float4 A = patch4[row][2*txg + 0];
            float4 B2 = patch4[row][2*txg + 1];
            float4 C2 = patch4[row][2*txg + 2];
            float4 D2 = patch4[row][2*txg + 3];
            float rv[16] = {A.x,A.y,A.z,A.w,B2.x,B2.y,B2.z,B2.w,
                            C2.x,C2.y,C2.z,C2.w,D2.x,D2.y,D2.z,D2.w};
            const float* wp = &wlds[c][pr][0];
            float wv[14];
            #pragma unroll
            for (int q = 0; q < 14; ++q) wv[q] = wp[q];
            #pragma unroll
            for (int kx = 0; kx < 7; ++kx) {
                float w0 = wv[2*kx], w1 = wv[2*kx+1];
                #pragma unroll
                for (int p = 0; p < 8; ++p) {
                    float v = rv[p + kx + 1];
                    acc0[p] = fmaf(w0, v, acc0[p]);
                    acc1[p] = fmaf(w1, v, acc1[p]);
                }
            }
        }
        __syncthreads();
    }

    float br0 = b_ref[0], br1 = b_ref[1];
    int y = row0 + tyg;
    int x0 = col0 + txg*8;
    #pragma unroll
    for (int p = 0; p < 8; ++p) {
        float t0 = tanhf(acc0[p] + br0);
        float t1 = tanhf(acc1[p] + br1);
        refmap[((size_t)(b*2 + 0)*512 + y)*512 + x0 + p] = t0 * 3.0f;
        refmap[((size_t)(b*2 + 1)*512 + y)*512 + x0 + p] = t1 * 3.0f;
    }
}

// ============================================================
// Kernel 4: exact top-512 on u32 fg bits (3-pass radix select),
//   ties by smallest index, bitonic (key desc, idx asc). [VERIFIED r3/r4]
// ============================================================
__device__ __forceinline__ void cpn_find_bucket(
    unsigned int* hist, unsigned int* seg, int nb, int target, int tid,
    int* s_bsel, int* s_cnt)
{
    int nseg = nb / 32;
    for (int t = tid; t < nseg; t += 1024) {
        unsigned int s = 0;
        for (int q = 0; q < 32; ++q) s += hist[t*32 + q];
        seg[t] = s;
    }
    __syncthreads();
    if (tid == 0) {
        int cum = 0, sg = 0;
        for (int jj = nseg - 1; jj >= 0; --jj) {
            int c = (int)seg[jj];
            if (cum + c >= target) { sg = jj; break; }
            cum += c;
        }
        int bs = sg*32;
        for (int jj = sg*32 + 31; jj >= sg*32; --jj) {
            int c = (int)hist[jj];
            if (cum + c >= target) { bs = jj; break; }
            cum += c;
        }
        *s_bsel = bs; *s_cnt = cum;
    }
    __syncthreads();
}

__global__ __launch_bounds__(1024) void cpn_topk_kernel(
    const float* __restrict__ fg, int* __restrict__ tidx, float* __restrict__ tscores)
{
    const int b = blockIdx.x;
    const int tid = threadIdx.x;
    const float* f = fg + (size_t)b * 65536;

    __shared__ unsigned int hist[2048];
    __shared__ unsigned int seg[64];
    __shared__ int tie[2048];
    __shared__ int sel_idx[512];
    __shared__ unsigned int skey[512];
    __shared__ int sidx[512];
    __shared__ int s_b, s_c, s_nsel, s_ntie;

    const int bitsA[3]  = {11,11,10};
    const int shiftA[3] = {21,10,0};

    unsigned int prefix = 0;
    int target = 512;
    for (int pass = 0; pass < 3; ++pass) {
        int sh = shiftA[pass], nb = 1 << bitsA[pass];
        for (int i = tid; i < 2048; i += 1024) hist[i] = 0;
        __syncthreads();
        if (pass == 0) {
            for (int i = tid; i < 65536; i += 1024) {
                unsigned int k = __float_as_uint(f[i]);
                atomicAdd(&hist[k >> 21], 1u);
            }
        } else {
            int hs = sh + bitsA[pass];
            for (int i = tid; i < 65536; i += 1024) {
                unsigned int k = __float_as_uint(f[i]);
                if ((k >> hs) == prefix)
                    atomicAdd(&hist[(k >> sh) & (nb-1)], 1u);
            }
        }
        __syncthreads();
        cpn_find_bucket(hist, seg, nb, target, tid, &s_b, &s_c);
        prefix = (prefix << bitsA[pass]) | (unsigned)s_b;
        target -= s_c;
    }
    if (tid == 0) { s_nsel = 0; s_ntie = 0; }
    __syncthreads();
    const unsigned int K = prefix;

    for (int i = tid; i < 65536; i += 1024) {
        unsigned int k = __float_as_uint(f[i]);
        if (k > K) { int q = atomicAdd(&s_nsel, 1); sel_idx[q] = i; }
        else if (k == K) { int q = atomicAdd(&s_ntie, 1); if (q < 2048) tie[q] = i; }
    }
    __syncthreads();
    int nsel = s_nsel;
    int nt = s_ntie; if (nt > 2048) nt = 2048;
    for (int q = tid; q < 2048; q += 1024) if (q >= nt) tie[q] = 0x7FFFFFFF;
    __syncthreads();

    for (int kk = 2; kk <= 2048; kk <<= 1)
        for (int jj = kk >> 1; jj > 0; jj >>= 1) {
            for (int i = tid; i < 2048; i += 1024) {
                int ixj = i ^ jj;
                if (ixj > i) {
                    int a = tie[i], c = tie[ixj];
                    bool up = ((i & kk) == 0);
                    if (up ? (a > c) : (a < c)) { tie[i] = c; tie[ixj] = a; }
                }
            }
            __syncthreads();
        }

    for (int q = tid; q < 512; q += 1024) {
        unsigned int k2; int i2;
        if (q < nsel) { i2 = sel_idx[q]; k2 = __float_as_uint(f[i2]); }
        else          { i2 = tie[q - nsel]; k2 = K; }
        skey[q] = k2; sidx[q] = i2;
    }
    __syncthreads();
    for (int kk = 2; kk <= 512; kk <<= 1)
        for (int jj = kk >> 1; jj > 0; jj >>= 1) {
            if (tid < 512) {
                int i = tid, ixj = i ^ jj;
                if (ixj > i) {
                    unsigned int ka = skey[i], kc = skey[ixj];
                    int ia = sidx[i], ic = sidx[ixj];
                    bool up = ((i & kk) == 0);
                    bool aBefore = (ka > kc) || (ka == kc && ia < ic);
                    if (up ? !aBefore : aBefore) {
                        skey[i] = kc; skey[ixj] = ka;
                        sidx[i] = ic; sidx[ixj] = ia;
                    }
                }
            }
            __syncthreads();
        }
    for (int q = tid; q < 512; q += 1024) {
        int i2 = sidx[q];
        tscores[b*512 + q] = f[i2];
        tidx[b*512 + q] = i2;
    }
}

// ============================================================
// Kernel 5: gathered 7x7x64 conv at top-k pts; f64 accum -> f32 out
// ============================================================
__global__ __launch_bounds__(256) void cpn_gather_conv_kernel(
    const float* __restrict__ cf, const float* __restrict__ wg,
    const float* __restrict__ b_loc, const float* __restrict__ b_fourier,
    const int* __restrict__ tidx, float* __restrict__ gath)
{
    const int b = blockIdx.y, p = blockIdx.x, tid = threadIdx.x;
    const int idx = tidx[b*512 + p];
    const int gy = idx >> 8, gx = idx & 255;

    double part[26];
    #pragma unroll
    for (int o = 0; o < 26; ++o) part[o] = 0.0;

    for (int t = tid; t < 3136; t += 256) {
        int c = t / 49, rr = t % 49, ky = rr / 7, kx = rr % 7;
        int y = gy + ky - 3, x = gx + kx - 3;
        float v = 0.f;
        if ((unsigned)y < 256u && (unsigned)x < 256u)
            v = cf[((size_t)(b*64 + c)*256 + y)*256 + x];
        const float* wr = wg + t*26;
        double dv = (double)v;
        #pragma unroll
        for (int o = 0; o < 26; ++o) part[o] = fma(dv, (double)wr[o], part[o]);
    }
    #pragma unroll
    for (int o = 0; o < 26; ++o)
        for (int off = 32; off; off >>= 1) part[o] += __shfl_down(part[o], off, 64);

    __shared__ double red[4][26];
    int w = tid >> 6, lane = tid & 63;
    if (lane == 0) {
        #pragma unroll
        for (int o = 0; o < 26; ++o) red[w][o] = part[o];
    }
    __syncthreads();
    if (tid < 26) {
        double s = red[0][tid] + red[1][tid] + red[2][tid] + red[3][tid];
        s += (tid < 2) ? (double)b_loc[tid] : (double)b_fourier[tid - 2];
        gath[((size_t)b*512 + p)*26 + tid] = (float)s;   // f32 layer boundary
    }
}

// ============================================================
// Kernel 6: fourier synthesis (table trig) + 4 refinement iters + boxes,
//   full f32 emulation (asm barriers block FMA contraction).
// ============================================================
__global__ __launch_bounds__(64) void cpn_contour_kernel(
    const float* __restrict__ gath, const int* __restrict__ tidx,
    const float* __restrict__ refmap, const float* __restrict__ trig,
    float* __restrict__ out_contour, float* __restrict__ out_boxes)
{
    const int bp = blockIdx.x;            // b*512 + p
    const int b = bp >> 9;
    const int s = threadIdx.x;            // 0..63
    const float* g = gath + (size_t)bp * 26;
    const int idx = tidx[bp];
    const int gy = idx >> 8, gx = idx & 255;

    float cx = ((float)gx + g[0]) * 2.0f;
    float cy = ((float)gy + g[1]) * 2.0f;

    float sxc = 0.f, sxs = 0.f, syc = 0.f, sys = 0.f;
    #pragma unroll
    for (int k = 0; k < 6; ++k) {
        float cs = trig[k*64 + s];
        float sn = trig[384 + k*64 + s];
        float t0 = g[2 + k*4 + 0] * cs; asm volatile("" : "+v"(t0)); sxc += t0;
        float t1 = g[2 + k*4 + 1] * sn; asm volatile("" : "+v"(t1)); sxs += t1;
        float t2 = g[2 + k*4 + 2] * cs; asm volatile("" : "+v"(t2)); syc += t2;
        float t3 = g[2 + k*4 + 3] * sn; asm volatile("" : "+v"(t3)); sys += t3;
    }
    float px = sxc + sxs;
    float py = syc + sys;
    float x = px * 2.0f; asm volatile("" : "+v"(x)); x += cx;
    float y = py * 2.0f; asm volatile("" : "+v"(y)); y += cy;

    const float* r0 = refmap + (size_t)b * 2 * 262144;
    const float* r1 = r0 + 262144;
    #pragma unroll
    for (int it = 0; it < 4; ++it) {
        float xr = rintf(x); xr = fminf(fmaxf(xr, 0.f), 511.f);
        float yr = rintf(y); yr = fminf(fmaxf(yr, 0.f), 511.f);
        int xi = (int)xr, yi = (int)yr;
        x += r0[yi*512 + xi];
        y += r1[yi*512 + xi];
    }

    out_contour[((size_t)bp*64 + s)*2 + 0] = x;
    out_contour[((size_t)bp*64 + s)*2 + 1] = y;

    float mnx = x, mxx = x, mny = y, mxy = y;
    #pragma unroll
    for (int off = 32; off; off >>= 1) {
        mnx = fminf(mnx, __shfl_xor(mnx, off, 64));
        mny = fminf(mny, __shfl_xor(mny, off, 64));
        mxx = fmaxf(mxx, __shfl_xor(mxx, off, 64));
        mxy = fmaxf(mxy, __shfl_xor(mxy, off, 64));
    }
    if (s == 0) {
        out_boxes[bp*4 + 0] = mnx;
        out_boxes[bp*4 + 1] = mny;
        out_boxes[bp*4 + 2] = mxx;
        out_boxes[bp*4 + 3] = mxy;
    }
}

// ============================================================
// Kernel 7: sequential NMS, literal f32 op order (reference semantics)
// ============================================================
__global__ __launch_bounds__(512) void cpn_nms_kernel(
    const float* __restrict__ boxes, const float* __restrict__ scores,
    float* __restrict__ keep_out)
{
    const int b = blockIdx.x;
    const int j = threadIdx.x;
    __shared__ float X1[512], Y1[512], X2[512], Y2[512], AR[512];
    __shared__ int keep[512];

    const float* bb = boxes + b*512*4;
    float x1 = bb[j*4+0], y1 = bb[j*4+1], x2 = bb[j*4+2], y2 = bb[j*4+3];
    float aj = fmaxf(x2 - x1, 0.f) * fmaxf(y2 - y1, 0.f);
    X1[j] = x1; Y1[j] = y1; X2[j] = x2; Y2[j] = y2; AR[j] = aj;
    keep[j] = (scores[b*512 + j] > 0.5f) ? 1 : 0;
    __syncthreads();

    for (int i = 0; i < 512; ++i) {
        if (keep[i] && j > i) {
            float ix1 = fmaxf(x1, X1[i]);
            float iy1 = fmaxf(y1, Y1[i]);
            float ix2 = fminf(x2, X2[i]);
            float iy2 = fminf(y2, Y2[i]);
            float inter = fmaxf(ix2 - ix1, 0.f) * fmaxf(iy2 - iy1, 0.f);
            float uni = (aj + AR[i]) - inter;
            float iou = inter / fmaxf(uni, 1e-8f);
            if (iou > 0.2f) keep[j] = 0;
        }
        __syncthreads();
    }
    keep_out[b*512 + j] = keep[j] ? 1.0f : 0.0f;
}

// ============================================================
extern "C" void kernel_launch(void* const* d_in, const int* in_sizes, int n_in,
                              void* d_out, int out_size, void* d_ws, size_t ws_size,
                              hipStream_t stream)
{
    if (ws_size < WS_END) return;   // defensive: avoid OOB scratch writes

    const float* cf   = (const float*)d_in[0];   // contour_features (4,64,256,256)
    const float* esf  = (const float*)d_in[1];   // enc_score_features
    const float* rff  = (const float*)d_in[2];   // refinement_features (4,32,512,512)
    const float* erf  = (const float*)d_in[3];   // enc_refinement_features
    const float* w_sr = (const float*)d_in[4];   // w_score_reduce (64,128,1,1)
    const float* w_s  = (const float*)d_in[5];   // w_score (2,64,7,7)
    const float* b_s  = (const float*)d_in[6];
    const float* w_l  = (const float*)d_in[7];   // w_loc (2,64,7,7)
    const float* b_l  = (const float*)d_in[8];
    const float* w_f  = (const float*)d_in[9];   // w_fourier (24,64,7,7)
    const float* b_f  = (const float*)d_in[10];
    const float* w_rr = (const float*)d_in[11];  // w_ref_reduce (32,64,1,1)
    const float* w_r  = (const float*)d_in[12];  // w_ref (2,32,7,7)
    const float* b_r  = (const float*)d_in[13];

    char* ws = (char*)d_ws;
    float*   fg   = (float*)(ws + WS_FG);
    float*   refm = (float*)(ws + WS_REF);
    double2* part = (double2*)(ws + WS_PART);
    double*  wse  = (double*)(ws + WS_WSE);
    double*  wre  = (double*)(ws + WS_WRE);
    float*   wg   = (float*)(ws + WS_WG);
    int*     tidx = (int*)(ws + WS_TIDX);
    float*   gath = (float*)(ws + WS_GATH);
    float*   trig = (float*)(ws + WS_TRIG);

    float* out_contour = (float*)d_out;                  // 4*512*64*2
    float* out_scores  = out_contour + 262144;           // 4*512
    float* out_keep    = out_scores + 2048;              // 4*512
    float* out_boxes   = out_keep + 2048;                // 4*512*4

    cpn_prep_kernel<<<dim3(395), dim3(256), 0, stream>>>(
        w_sr, w_s, w_l, w_f, w_rr, w_r, wse, wre, wg, trig);
    cpn_score_conv_kernel<<<dim3(8, 8, 8), dim3(256), 0, stream>>>(
        cf, esf, wse, part);
    cpn_ref_conv_kernel<<<dim3(8, 16, 4), dim3(256), 0, stream>>>(
        rff, erf, wre, b_r, refm);
    cpn_score_fin_kernel<<<dim3(1024), dim3(256), 0, stream>>>(
        part, b_s, fg);
    cpn_topk_kernel<<<dim3(4), dim3(1024), 0, stream>>>(fg, tidx, out_scores);
    cpn_gather_conv_kernel<<<dim3(512, 4), dim3(256), 0, stream>>>(
        cf, wg, b_l, b_f, tidx, gath);
    cpn_contour_kernel<<<dim3(2048), dim3(64), 0, stream>>>(
        gath, tidx, refm, trig, out_contour, out_boxes);
    cpn_nms_kernel<<<dim3(4), dim3(512), 0, stream>>>(
        out_boxes, out_scores, out_keep);
}

// Round 7
// 724.071 us; speedup vs baseline: 1.2807x; 1.0018x over previous
//
#include <hip/hip_runtime.h>
#include <math.h>

// ---------------- workspace layout (bytes, all 16-aligned) ----------------
#define WS_FG    0ull                          // fg f32: 4*65536*4 = 1 MB
#define WS_REF   3145728ull                    // refmap f32: 4*2*512*512*4 = 8 MB
#define WS_PART  11534336ull                   // score partials double2 [2][4][65536] = 8 MB
#define WS_WSE   19922944ull                   // W_score_eff f64 [2][128][49]
#define WS_WRE   20023296ull                   // W_ref_eff f64 [2][64][49]
#define WS_WG    20073472ull                   // gather weights f32 [3136][26]
#define WS_TIDX  20399616ull                   // top_idx int [4][512]
#define WS_GATH  20407808ull                   // gathered f32 [4][512][26]
#define WS_TRIG  20620800ull                   // trig table f32 [2][6][64]
#define WS_END   20899328ull

// ============================================================
// Kernel 1: composed weights (f64) + gather-layout copies + trig table
// ============================================================
__global__ __launch_bounds__(256) void cpn_prep_kernel(
    const float* __restrict__ w_score_reduce, const float* __restrict__ w_score,
    const float* __restrict__ w_loc, const float* __restrict__ w_fourier,
    const float* __restrict__ w_ref_reduce, const float* __restrict__ w_ref,
    double* __restrict__ wse, double* __restrict__ wre, float* __restrict__ wg,
    float* __restrict__ trig)
{
    int i = blockIdx.x * 256 + threadIdx.x;
    if (i < 12544) {                    // 2*128*49
        int o = i / 6272;
        int rem = i % 6272;
        int c = rem / 49, r = rem % 49;
        double a = 0.0;
        for (int m = 0; m < 64; ++m)
            a += (double)w_score[(o*64 + m)*49 + r] * (double)w_score_reduce[m*128 + c];
        wse[i] = a;                     // layout [o][c][r]
    } else if (i < 12544 + 6272) {      // 2*64*49
        int t = i - 12544;
        int o = t / 3136;
        int rem = t % 3136;
        int c = rem / 49, r = rem % 49;
        double a = 0.0;
        for (int m = 0; m < 32; ++m)
            a += (double)w_ref[(o*32 + m)*49 + r] * (double)w_ref_reduce[m*64 + c];
        wre[t] = a;                     // layout [o][c][r]
    } else if (i < 12544 + 6272 + 81536) { // 3136*26
        int t = i - 18816;
        int tap = t / 26, o = t % 26;
        wg[t] = (o < 2) ? w_loc[o*3136 + tap] : w_fourier[(o - 2)*3136 + tap];
    } else if (i < 100352 + 768) {      // trig table, bit-identical f32 chain
        int t = i - 100352;             // 0..767 : [cs][k][s]
        int cs = t / 384;
        int k = (t % 384) / 64, s = t % 64;
        const float TWO_PI_F = (float)6.283185307179586;
        float a1 = TWO_PI_F * (float)(k + 1);   // f32 round
        float tf = (float)s * 0.015625f;        // exact
        float ang = a1 * tf;                    // f32 round
        double av = (double)ang;
        trig[t] = (cs == 0) ? (float)cos(av) : (float)sin(av);
    }
}

// ============================================================
// Kernel 2a: score conv HALF (64 channels), f64 accumulation.
//   blockIdx.z = b*2 + half; half0 reads cf, half1 reads esf.
//   Writes double2 (l0,l1) partials. Inner structure = verified r3/r4.
// ============================================================
__global__ __launch_bounds__(256) void cpn_score_conv_kernel(
    const float* __restrict__ cf, const float* __restrict__ esf,
    const double* __restrict__ wse, double2* __restrict__ partial)
{
    __shared__ __align__(16) double wch[32][7][14];    // 25088 B
    __shared__ __align__(16) float patch[38*44];       // 6688 B
    const int tid  = threadIdx.x;
    const int b    = blockIdx.z >> 1;
    const int half = blockIdx.z & 1;
    const int c0   = half * 64;
    const float* src = half ? esf : cf;
    const int row0 = blockIdx.y * 32;
    const int col0 = blockIdx.x * 32;
    const int ty   = tid >> 3;      // 0..31
    const int txg  = tid & 7;       // 0..7 -> 4 cols each

    double acc0[4] = {0.0,0.0,0.0,0.0};
    double acc1[4] = {0.0,0.0,0.0,0.0};
    float sreg[6];

    {   // prefetch channel 0 of this half's source
        const float* sp = src + (size_t)(b*64) * 65536;
        #pragma unroll
        for (int k = 0; k < 6; ++k) {
            int i = k*256 + tid; float v = 0.f;
            if (i < 1520) {
                int r = i/40, j = i%40;
                int gy = row0 - 3 + r, gx = col0 - 4 + j;
                if ((unsigned)gy < 256u && (unsigned)gx < 256u) v = sp[gy*256 + gx];
            }
            sreg[k] = v;
        }
    }

    for (int c = 0; c < 64; ++c) {
        if ((c & 31) == 0) {      // refresh weight chunk
            for (int i = tid; i < 32*98; i += 256) {
                int cc = i / 98, r = i % 98;
                int ky = r / 14, q = r % 14;
                int kx = q >> 1, o = q & 1;
                wch[cc][ky][q] = wse[o*6272 + (c0 + c + cc)*49 + ky*7 + kx];
            }
        }
        #pragma unroll
        for (int k = 0; k < 6; ++k) {
            int i = k*256 + tid;
            if (i < 1520) patch[(i/40)*44 + (i%40)] = sreg[k];
        }
        __syncthreads();
        if (c + 1 < 64) {   // prefetch next channel while computing this one
            const float* sp = src + (size_t)(b*64 + (c+1)) * 65536;
            #pragma unroll
            for (int k = 0; k < 6; ++k) {
                int i = k*256 + tid; float v = 0.f;
                if (i < 1520) {
                    int r = i/40, j = i%40;
                    int gy = row0 - 3 + r, gx = col0 - 4 + j;
                    if ((unsigned)gy < 256u && (unsigned)gx < 256u) v = sp[gy*256 + gx];
                }
                sreg[k] = v;
            }
        }
        const int cl = c & 31;
        #pragma unroll
        for (int ky = 0; ky < 7; ++ky) {
            const float4* pr = reinterpret_cast<const float4*>(&patch[(ty+ky)*44 + txg*4]);
            float4 A = pr[0], B2 = pr[1], C2 = pr[2];
            float rv[12] = {A.x,A.y,A.z,A.w,B2.x,B2.y,B2.z,B2.w,C2.x,C2.y,C2.z,C2.w};
            const double* wp = &wch[cl][ky][0];
            #pragma unroll
            for (int kx = 0; kx < 7; ++kx) {
                double w0 = wp[2*kx], w1 = wp[2*kx+1];
                #pragma unroll
                for (int p = 0; p < 4; ++p) {
                    double v = (double)rv[p + kx + 1];
                    acc0[p] = fma(w0, v, acc0[p]);
                    acc1[p] = fma(w1, v, acc1[p]);
                }
            }
        }
        __syncthreads();
    }

    int y = row0 + ty;
    #pragma unroll
    for (int p = 0; p < 4; ++p) {
        int x = col0 + txg*4 + p;
        double2 v; v.x = acc0[p]; v.y = acc1[p];
        partial[(size_t)(half*4 + b)*65536 + y*256 + x] = v;
    }
}

// ============================================================
// Kernel 2b: score finalize: sum halves + bias, then LITERAL f32
//   log_softmax->exp chain (verified r3/r4).
// ============================================================
__global__ __launch_bounds__(256) void cpn_score_fin_kernel(
    const double2* __restrict__ partial, const float* __restrict__ b_score,
    float* __restrict__ fg)
{
    int i = blockIdx.x * 256 + threadIdx.x;    // 0..262143
    int b = i >> 16, px = i & 65535;
    double2 p0 = partial[(size_t)b*65536 + px];
    double2 p1 = partial[(size_t)(4 + b)*65536 + px];
    double bs0 = (double)b_score[0], bs1 = (double)b_score[1];
    float l0f = (float)((p0.x + p1.x) + bs0);
    float l1f = (float)((p0.y + p1.y) + bs1);
    float m  = fmaxf(l0f, l1f);
    float e0 = (float)exp((double)(l0f - m));
    float e1 = (float)exp((double)(l1f - m));
    float s  = e0 + e1;
    float lg = (float)log((double)s);
    float ls1 = (l1f - m) - lg;
    float fgv = (float)exp((double)ls1);
    fg[i] = fgv;
}

// ============================================================
// Kernel 3: refinement conv (64->2, 7x7, pad3), pure f32.
//   64x32 tile, 1 row x 8 px/thread.
//   Lane remap (tyg=tid&31, txg=tid>>5): 8 consecutive lanes hit 8
//   different patch rows -> bank starts {0,12,24,4,16,28,8,20} -> all
//   32 banks per fixed HW phase group -> conflict-free ds_read_b128.
//   Per-pixel accumulation order unchanged (bit-identical refmap).
// ============================================================
__global__ __launch_bounds__(256) void cpn_ref_conv_kernel(
    const float* __restrict__ rff, const float* __restrict__ erf,
    const double* __restrict__ wre, const float* __restrict__ b_ref,
    float* __restrict__ refmap)
{
    __shared__ __align__(16) float4 patch4[38][19];    // 38 rows x 76 floats = 11552 B
    __shared__ __align__(16) float wlds[64][7][14];    // 25088 B  (total 36.6 KB)
    const int tid  = threadIdx.x;
    const int b    = blockIdx.z;
    const int row0 = blockIdx.y * 32;
    const int col0 = blockIdx.x * 64;
    const int tyg  = tid & 31;      // 0..31 -> 1 output row each   [REMAPPED]
    const int txg  = tid >> 5;      // 0..7  -> 8 px each           [REMAPPED]

    for (int i = tid; i < 64*98; i += 256) {
        int c = i / 98, r = i % 98;
        int ky = r / 14, q = r % 14;
        int kx = q >> 1, o = q & 1;
        wlds[c][ky][q] = (float)wre[o*3136 + c*49 + ky*7 + kx];
    }

    // precompute staging slots (constant per thread): 38 rows x 18 float4 = 684
    int   st_r[3], st_f[3];
    long  st_off[3];
    bool  st_ok[3];
    #pragma unroll
    for (int k = 0; k < 3; ++k) {
        int i = k*256 + tid;
        int r = i / 18, f = i % 18;
        int gy = row0 - 3 + r, gx = col0 - 4 + 4*f;
        st_r[k] = r; st_f[k] = f;
        st_ok[k] = (i < 684) && ((unsigned)gy < 512u) && ((unsigned)gx < 509u);
        st_off[k] = (long)gy * 512 + gx;
    }

    float4 s4[3];
    {   // prefetch channel 0
        const float* sp = rff + (size_t)(b*32) * 262144;
        #pragma unroll
        for (int k = 0; k < 3; ++k) {
            float4 v = {0.f,0.f,0.f,0.f};
            if (st_ok[k]) v = *reinterpret_cast<const float4*>(sp + st_off[k]);
            s4[k] = v;
        }
    }

    float acc0[8] = {0,0,0,0,0,0,0,0};
    float acc1[8] = {0,0,0,0,0,0,0,0};

    for (int c = 0; c < 64; ++c) {
        #pragma unroll
        for (int k = 0; k < 3; ++k) {
            int i = k*256 + tid;
            if (i < 684) patch4[st_r[k]][st_f[k]] = s4[k];
        }
        __syncthreads();
        if (c + 1 < 64) {
            int cn = c + 1;
            const float* src = (cn < 32) ? rff : erf;
            const float* sp = src + (size_t)(b*32 + (cn & 31)) * 262144;
            #pragma unroll
            for (int k = 0; k < 3; ++k) {
                float4 v = {0.f,0.f,0.f,0.f};
                if (st_ok[k]) v = *reinterpret_cast<const float4*>(sp + st_off[k]);
                s4[k] = v;
            }
        }
        #pragma unroll
        for (int pr = 0; pr < 7; ++pr) {       // pr == ky
            int row = tyg + pr;
            float4 A = patch4[row][2*txg + 0];
            float4 B2 = patch4[row][2*txg + 1];
            float4 C2 = patch4[row][2*txg + 2];
            float4 D2 = patch4[row][2*txg + 3];
            float rv[16] = {A.x,A.y,A.z,A.w,B2.x,B2.y,B2.z,B2.w,
                            C2.x,C2.y,C2.z,C2.w,D2.x,D2.y,D2.z,D2.w};
            const float* wp = &wlds[c][pr][0];
            float wv[14];
            #pragma unroll
            for (int q = 0; q < 14; ++q) wv[q] = wp[q];
            #pragma unroll
            for (int kx = 0; kx < 7; ++kx) {
                float w0 = wv[2*kx], w1 = wv[2*kx+1];
                #pragma unroll
                for (int p = 0; p < 8; ++p) {
                    float v = rv[p + kx + 1];
                    acc0[p] = fmaf(w0, v, acc0[p]);
                    acc1[p] = fmaf(w1, v, acc1[p]);
                }
            }
        }
        __syncthreads();
    }

    float br0 = b_ref[0], br1 = b_ref[1];
    int y = row0 + tyg;
    int x0 = col0 + txg*8;
    #pragma unroll
    for (int p = 0; p < 8; ++p) {
        float t0 = tanhf(acc0[p] + br0);
        float t1 = tanhf(acc1[p] + br1);
        refmap[((size_t)(b*2 + 0)*512 + y)*512 + x0 + p] = t0 * 3.0f;
        refmap[((size_t)(b*2 + 1)*512 + y)*512 + x0 + p] = t1 * 3.0f;
    }
}

// ============================================================
// Kernel 4: exact top-512 on u32 fg bits (3-pass radix select),
//   ties by smallest index, bitonic (key desc, idx asc). [VERIFIED r3/r4]
// ============================================================
__device__ __forceinline__ void cpn_find_bucket(
    unsigned int* hist, unsigned int* seg, int nb, int target, int tid,
    int* s_bsel, int* s_cnt)
{
    int nseg = nb / 32;
    for (int t = tid; t < nseg; t += 1024) {
        unsigned int s = 0;
        for (int q = 0; q < 32; ++q) s += hist[t*32 + q];
        seg[t] = s;
    }
    __syncthreads();
    if (tid == 0) {
        int cum = 0, sg = 0;
        for (int jj = nseg - 1; jj >= 0; --jj) {
            int c = (int)seg[jj];
            if (cum + c >= target) { sg = jj; break; }
            cum += c;
        }
        int bs = sg*32;
        for (int jj = sg*32 + 31; jj >= sg*32; --jj) {
            int c = (int)hist[jj];
            if (cum + c >= target) { bs = jj; break; }
            cum += c;
        }
        *s_bsel = bs; *s_cnt = cum;
    }
    __syncthreads();
}

__global__ __launch_bounds__(1024) void cpn_topk_kernel(
    const float* __restrict__ fg, int* __restrict__ tidx, float* __restrict__ tscores)
{
    const int b = blockIdx.x;
    const int tid = threadIdx.x;
    const float* f = fg + (size_t)b * 65536;

    __shared__ unsigned int hist[2048];
    __shared__ unsigned int seg[64];
    __shared__ int tie[2048];
    __shared__ int sel_idx[512];
    __shared__ unsigned int skey[512];
    __shared__ int sidx[512];
    __shared__ int s_b, s_c, s_nsel, s_ntie;

    const int bitsA[3]  = {11,11,10};
    const int shiftA[3] = {21,10,0};

    unsigned int prefix = 0;
    int target = 512;
    for (int pass = 0; pass < 3; ++pass) {
        int sh = shiftA[pass], nb = 1 << bitsA[pass];
        for (int i = tid; i < 2048; i += 1024) hist[i] = 0;
        __syncthreads();
        if (pass == 0) {
            for (int i = tid; i < 65536; i += 1024) {
                unsigned int k = __float_as_uint(f[i]);
                atomicAdd(&hist[k >> 21], 1u);
            }
        } else {
            int hs = sh + bitsA[pass];
            for (int i = tid; i < 65536; i += 1024) {
                unsigned int k = __float_as_uint(f[i]);
                if ((k >> hs) == prefix)
                    atomicAdd(&hist[(k >> sh) & (nb-1)], 1u);
            }
        }
        __syncthreads();
        cpn_find_bucket(hist, seg, nb, target, tid, &s_b, &s_c);
        prefix = (prefix << bitsA[pass]) | (unsigned)s_b;
        target -= s_c;
    }
    if (tid == 0) { s_nsel = 0; s_ntie = 0; }
    __syncthreads();
    const unsigned int K = prefix;

    for (int i = tid; i < 65536; i += 1024) {
        unsigned int k = __float_as_uint(f[i]);
        if (k > K) { int q = atomicAdd(&s_nsel, 1); sel_idx[q] = i; }
        else if (k == K) { int q = atomicAdd(&s_ntie, 1); if (q < 2048) tie[q] = i; }
    }
    __syncthreads();
    int nsel = s_nsel;
    int nt = s_ntie; if (nt > 2048) nt = 2048;
    for (int q = tid; q < 2048; q += 1024) if (q >= nt) tie[q] = 0x7FFFFFFF;
    __syncthreads();

    for (int kk = 2; kk <= 2048; kk <<= 1)
        for (int jj = kk >> 1; jj > 0; jj >>= 1) {
            for (int i = tid; i < 2048; i += 1024) {
                int ixj = i ^ jj;
                if (ixj > i) {
                    int a = tie[i], c = tie[ixj];
                    bool up = ((i & kk) == 0);
                    if (up ? (a > c) : (a < c)) { tie[i] = c; tie[ixj] = a; }
                }
            }
            __syncthreads();
        }

    for (int q = tid; q < 512; q += 1024) {
        unsigned int k2; int i2;
        if (q < nsel) { i2 = sel_idx[q]; k2 = __float_as_uint(f[i2]); }
        else          { i2 = tie[q - nsel]; k2 = K; }
        skey[q] = k2; sidx[q] = i2;
    }
    __syncthreads();
    for (int kk = 2; kk <= 512; kk <<= 1)
        for (int jj = kk >> 1; jj > 0; jj >>= 1) {
            if (tid < 512) {
                int i = tid, ixj = i ^ jj;
                if (ixj > i) {
                    unsigned int ka = skey[i], kc = skey[ixj];
                    int ia = sidx[i], ic = sidx[ixj];
                    bool up = ((i & kk) == 0);
                    bool aBefore = (ka > kc) || (ka == kc && ia < ic);
                    if (up ? !aBefore : aBefore) {
                        skey[i] = kc; skey[ixj] = ka;
                        sidx[i] = ic; sidx[ixj] = ia;
                    }
                }
            }
            __syncthreads();
        }
    for (int q = tid; q < 512; q += 1024) {
        int i2 = sidx[q];
        tscores[b*512 + q] = f[i2];
        tidx[b*512 + q] = i2;
    }
}

// ============================================================
// Kernel 5: gathered 7x7x64 conv at top-k pts; f64 accum -> f32 out
// ============================================================
__global__ __launch_bounds__(256) void cpn_gather_conv_kernel(
    const float* __restrict__ cf, const float* __restrict__ wg,
    const float* __restrict__ b_loc, const float* __restrict__ b_fourier,
    const int* __restrict__ tidx, float* __restrict__ gath)
{
    const int b = blockIdx.y, p = blockIdx.x, tid = threadIdx.x;
    const int idx = tidx[b*512 + p];
    const int gy = idx >> 8, gx = idx & 255;

    double part[26];
    #pragma unroll
    for (int o = 0; o < 26; ++o) part[o] = 0.0;

    for (int t = tid; t < 3136; t += 256) {
        int c = t / 49, rr = t % 49, ky = rr / 7, kx = rr % 7;
        int y = gy + ky - 3, x = gx + kx - 3;
        float v = 0.f;
        if ((unsigned)y < 256u && (unsigned)x < 256u)
            v = cf[((size_t)(b*64 + c)*256 + y)*256 + x];
        const float* wr = wg + t*26;
        double dv = (double)v;
        #pragma unroll
        for (int o = 0; o < 26; ++o) part[o] = fma(dv, (double)wr[o], part[o]);
    }
    #pragma unroll
    for (int o = 0; o < 26; ++o)
        for (int off = 32; off; off >>= 1) part[o] += __shfl_down(part[o], off, 64);

    __shared__ double red[4][26];
    int w = tid >> 6, lane = tid & 63;
    if (lane == 0) {
        #pragma unroll
        for (int o = 0; o < 26; ++o) red[w][o] = part[o];
    }
    __syncthreads();
    if (tid < 26) {
        double s = red[0][tid] + red[1][tid] + red[2][tid] + red[3][tid];
        s += (tid < 2) ? (double)b_loc[tid] : (double)b_fourier[tid - 2];
        gath[((size_t)b*512 + p)*26 + tid] = (float)s;   // f32 layer boundary
    }
}

// ============================================================
// Kernel 6: fourier synthesis (table trig) + 4 refinement iters + boxes,
//   full f32 emulation (asm barriers block FMA contraction).
// ============================================================
__global__ __launch_bounds__(64) void cpn_contour_kernel(
    const float* __restrict__ gath, const int* __restrict__ tidx,
    const float* __restrict__ refmap, const float* __restrict__ trig,
    float* __restrict__ out_contour, float* __restrict__ out_boxes)
{
    const int bp = blockIdx.x;            // b*512 + p
    const int b = bp >> 9;
    const int s = threadIdx.x;            // 0..63
    const float* g = gath + (size_t)bp * 26;
    const int idx = tidx[bp];
    const int gy = idx >> 8, gx = idx & 255;

    float cx = ((float)gx + g[0]) * 2.0f;
    float cy = ((float)gy + g[1]) * 2.0f;

    float sxc = 0.f, sxs = 0.f, syc = 0.f, sys = 0.f;
    #pragma unroll
    for (int k = 0; k < 6; ++k) {
        float cs = trig[k*64 + s];
        float sn = trig[384 + k*64 + s];
        float t0 = g[2 + k*4 + 0] * cs; asm volatile("" : "+v"(t0)); sxc += t0;
        float t1 = g[2 + k*4 + 1] * sn; asm volatile("" : "+v"(t1)); sxs += t1;
        float t2 = g[2 + k*4 + 2] * cs; asm volatile("" : "+v"(t2)); syc += t2;
        float t3 = g[2 + k*4 + 3] * sn; asm volatile("" : "+v"(t3)); sys += t3;
    }
    float px = sxc + sxs;
    float py = syc + sys;
    float x = px * 2.0f; asm volatile("" : "+v"(x)); x += cx;
    float y = py * 2.0f; asm volatile("" : "+v"(y)); y += cy;

    const float* r0 = refmap + (size_t)b * 2 * 262144;
    const float* r1 = r0 + 262144;
    #pragma unroll
    for (int it = 0; it < 4; ++it) {
        float xr = rintf(x); xr = fminf(fmaxf(xr, 0.f), 511.f);
        float yr = rintf(y); yr = fminf(fmaxf(yr, 0.f), 511.f);
        int xi = (int)xr, yi = (int)yr;
        x += r0[yi*512 + xi];
        y += r1[yi*512 + xi];
    }

    out_contour[((size_t)bp*64 + s)*2 + 0] = x;
    out_contour[((size_t)bp*64 + s)*2 + 1] = y;

    float mnx = x, mxx = x, mny = y, mxy = y;
    #pragma unroll
    for (int off = 32; off; off >>= 1) {
        mnx = fminf(mnx, __shfl_xor(mnx, off, 64));
        mny = fminf(mny, __shfl_xor(mny, off, 64));
        mxx = fmaxf(mxx, __shfl_xor(mxx, off, 64));
        mxy = fmaxf(mxy, __shfl_xor(mxy, off, 64));
    }
    if (s == 0) {
        out_boxes[bp*4 + 0] = mnx;
        out_boxes[bp*4 + 1] = mny;
        out_boxes[bp*4 + 2] = mxx;
        out_boxes[bp*4 + 3] = mxy;
    }
}

// ============================================================
// Kernel 7: sequential NMS, literal f32 op order (reference semantics)
// ============================================================
__global__ __launch_bounds__(512) void cpn_nms_kernel(
    const float* __restrict__ boxes, const float* __restrict__ scores,
    float* __restrict__ keep_out)
{
    const int b = blockIdx.x;
    const int j = threadIdx.x;
    __shared__ float X1[512], Y1[512], X2[512], Y2[512], AR[512];
    __shared__ int keep[512];

    const float* bb = boxes + b*512*4;
    float x1 = bb[j*4+0], y1 = bb[j*4+1], x2 = bb[j*4+2], y2 = bb[j*4+3];
    float aj = fmaxf(x2 - x1, 0.f) * fmaxf(y2 - y1, 0.f);
    X1[j] = x1; Y1[j] = y1; X2[j] = x2; Y2[j] = y2; AR[j] = aj;
    keep[j] = (scores[b*512 + j] > 0.5f) ? 1 : 0;
    __syncthreads();

    for (int i = 0; i < 512; ++i) {
        if (keep[i] && j > i) {
            float ix1 = fmaxf(x1, X1[i]);
            float iy1 = fmaxf(y1, Y1[i]);
            float ix2 = fminf(x2, X2[i]);
            float iy2 = fminf(y2, Y2[i]);
            float inter = fmaxf(ix2 - ix1, 0.f) * fmaxf(iy2 - iy1, 0.f);
            float uni = (aj + AR[i]) - inter;
            float iou = inter / fmaxf(uni, 1e-8f);
            if (iou > 0.2f) keep[j] = 0;
        }
        __syncthreads();
    }
    keep_out[b*512 + j] = keep[j] ? 1.0f : 0.0f;
}

// ============================================================
extern "C" void kernel_launch(void* const* d_in, const int* in_sizes, int n_in,
                              void* d_out, int out_size, void* d_ws, size_t ws_size,
                              hipStream_t stream)
{
    if (ws_size < WS_END) return;   // defensive: avoid OOB scratch writes

    const float* cf   = (const float*)d_in[0];   // contour_features (4,64,256,256)
    const float* esf  = (const float*)d_in[1];   // enc_score_features
    const float* rff  = (const float*)d_in[2];   // refinement_features (4,32,512,512)
    const float* erf  = (const float*)d_in[3];   // enc_refinement_features
    const float* w_sr = (const float*)d_in[4];   // w_score_reduce (64,128,1,1)
    const float* w_s  = (const float*)d_in[5];   // w_score (2,64,7,7)
    const float* b_s  = (const float*)d_in[6];
    const float* w_l  = (const float*)d_in[7];   // w_loc (2,64,7,7)
    const float* b_l  = (const float*)d_in[8];
    const float* w_f  = (const float*)d_in[9];   // w_fourier (24,64,7,7)
    const float* b_f  = (const float*)d_in[10];
    const float* w_rr = (const float*)d_in[11];  // w_ref_reduce (32,64,1,1)
    const float* w_r  = (const float*)d_in[12];  // w_ref (2,32,7,7)
    const float* b_r  = (const float*)d_in[13];

    char* ws = (char*)d_ws;
    float*   fg   = (float*)(ws + WS_FG);
    float*   refm = (float*)(ws + WS_REF);
    double2* part = (double2*)(ws + WS_PART);
    double*  wse  = (double*)(ws + WS_WSE);
    double*  wre  = (double*)(ws + WS_WRE);
    float*   wg   = (float*)(ws + WS_WG);
    int*     tidx = (int*)(ws + WS_TIDX);
    float*   gath = (float*)(ws + WS_GATH);
    float*   trig = (float*)(ws + WS_TRIG);

    float* out_contour = (float*)d_out;                  // 4*512*64*2
    float* out_scores  = out_contour + 262144;           // 4*512
    float* out_keep    = out_scores + 2048;              // 4*512
    float* out_boxes   = out_keep + 2048;                // 4*512*4

    cpn_prep_kernel<<<dim3(395), dim3(256), 0, stream>>>(
        w_sr, w_s, w_l, w_f, w_rr, w_r, wse, wre, wg, trig);
    cpn_score_conv_kernel<<<dim3(8, 8, 8), dim3(256), 0, stream>>>(
        cf, esf, wse, part);
    cpn_ref_conv_kernel<<<dim3(8, 16, 4), dim3(256), 0, stream>>>(
        rff, erf, wre, b_r, refm);
    cpn_score_fin_kernel<<<dim3(1024), dim3(256), 0, stream>>>(
        part, b_s, fg);
    cpn_topk_kernel<<<dim3(4), dim3(1024), 0, stream>>>(fg, tidx, out_scores);
    cpn_gather_conv_kernel<<<dim3(512, 4), dim3(256), 0, stream>>>(
        cf, wg, b_l, b_f, tidx, gath);
    cpn_contour_kernel<<<dim3(2048), dim3(64), 0, stream>>>(
        gath, tidx, refm, trig, out_contour, out_boxes);
    cpn_nms_kernel<<<dim3(4), dim3(512), 0, stream>>>(
        out_boxes, out_scores, out_keep);
}